// Round 4
// 71.451 us; speedup vs baseline: 1.0188x; 1.0188x over previous
//
#include <hip/hip_runtime.h>
#include <math.h>

// CapsuleLayer dynamic routing, fused single kernel.
// B=8, I=32, C=8, HW=256, O=16, h=16, NUM_ROUTING=3.
// Block = 4 consecutive pixels (same b), 512 threads = 8 waves (was 4).
//   wave w: owns i-slice [4w, 4w+4) for votes/distances/softmax rows,
//           waves 0-3 additionally own pixel p=w for combine/squash.
//   lane l: owns m = 4l..4l+3  (o = l>>2, h = (l&3)*4+j)
// Votes: float4 v[4][4] = 64 VGPRs -> __launch_bounds__(512,4) = 16 waves/CU
// (2x occupancy of previous 256-thread/128-VGPR version).
// Wave-private LDS handoffs (route, logits) use s_waitcnt lgkmcnt(0) instead
// of s_barrier; block barriers reduced to 2 per routing iteration.

#define PSTR 80    // p-stride (floats) for s_logits/s_route: 80 % 32 == 16
                   // -> logits scatter write (l&3)*PSTR + (l>>2) is exactly
                   //    2-way bank aliased (free), vs 4-way at stride 64.
#define WSTR (4 * PSTR)

__device__ __forceinline__ float4 f4zero() { return make_float4(0.f, 0.f, 0.f, 0.f); }

__device__ __forceinline__ void fma4(float4& a, float s, const float4& q) {
    a.x = fmaf(s, q.x, a.x); a.y = fmaf(s, q.y, a.y);
    a.z = fmaf(s, q.z, a.z); a.w = fmaf(s, q.w, a.w);
}

// Wave-private LDS producer->consumer handoff. The wave executes in lockstep,
// DS ops retire in order: draining lgkmcnt makes all lanes' writes visible to
// all lanes' subsequent reads. No s_barrier needed.
__device__ __forceinline__ void wave_lds_fence() {
    __builtin_amdgcn_sched_barrier(0);
    asm volatile("s_waitcnt lgkmcnt(0)" ::: "memory");
    __builtin_amdgcn_sched_barrier(0);
}

__global__ __launch_bounds__(512, 4)
void caps_kernel(const float* __restrict__ x,
                 const float* __restrict__ wgt,
                 const float* __restrict__ bias,
                 float* __restrict__ out)
{
    __shared__ float s_logits[8 * WSTR];  // [w][p (stride 80)][ii*16 + o]
    __shared__ float s_route [8 * WSTR];  // same layout
    __shared__ float s_part  [32 * 256];  // [w*4+p][m]  cross-wave preact partials
    __shared__ float s_act   [4 * 256];   // [p][m]

    const int t   = threadIdx.x;
    const int w   = t >> 6;                 // wave id (0..7)
    const int l   = t & 63;                 // lane id
    const int b   = blockIdx.x >> 6;        // batch
    const int hw0 = (blockIdx.x & 63) << 2; // first of 4 pixels

    const float4 bias4 = ((const float4*)bias)[l];   // bias[4l..4l+3]

    // ---------------- votes: v[ii][p] = sum_c x[b,i,c,hw0+p] * W[i,c,4l..4l+3]
    float4 v[4][4];
    {
        const float*  xb = x + (size_t)b * 65536 + hw0;
        const float4* w4 = (const float4*)wgt;
        #pragma unroll
        for (int ii = 0; ii < 4; ++ii) {
            const int i = __builtin_amdgcn_readfirstlane((w << 2) + ii); // SGPR -> s_load for x
            #pragma unroll
            for (int p = 0; p < 4; ++p) v[ii][p] = f4zero();
            #pragma unroll
            for (int c = 0; c < 8; ++c) {
                const float4 wv = w4[i * 512 + c * 64 + l];                 // coalesced dwordx4, L2-resident
                const float4 xv = *(const float4*)(xb + (i * 8 + c) * 256); // wave-uniform -> s_load
                fma4(v[ii][0], xv.x, wv);
                fma4(v[ii][1], xv.y, wv);
                fma4(v[ii][2], xv.z, wv);
                fma4(v[ii][3], xv.w, wv);
            }
        }
    }

    #pragma unroll
    for (int it = 0; it < 3; ++it) {
        float4 pre[4];
        if (it == 0) {
            // softmax of zero logits == 1/16 exactly: skip softmax entirely
            #pragma unroll
            for (int p = 0; p < 4; ++p) {
                float4 s = v[0][p];
                #pragma unroll
                for (int ii = 1; ii < 4; ++ii) {
                    s.x += v[ii][p].x; s.y += v[ii][p].y;
                    s.z += v[ii][p].z; s.w += v[ii][p].w;
                }
                pre[p] = make_float4(s.x * 0.0625f, s.y * 0.0625f,
                                     s.z * 0.0625f, s.w * 0.0625f);
            }
        } else {
            // softmax over o for this wave's 16 rows (4 ii x 4 p).
            // lane l: row r = l>>2 (p = r>>2, ii = r&3), o-quad = (l&3)*4
            const int base = w * WSTR + (l >> 4) * PSTR + ((l >> 2) & 3) * 16 + (l & 3) * 4;
            const float4 la = *(const float4*)&s_logits[base];
            float mx = fmaxf(fmaxf(la.x, la.y), fmaxf(la.z, la.w));
            mx = fmaxf(mx, __shfl_xor(mx, 1));
            mx = fmaxf(mx, __shfl_xor(mx, 2));
            const float e0 = __expf(la.x - mx), e1 = __expf(la.y - mx);
            const float e2 = __expf(la.z - mx), e3 = __expf(la.w - mx);
            float sum = (e0 + e1) + (e2 + e3);
            sum += __shfl_xor(sum, 1);
            sum += __shfl_xor(sum, 2);
            const float inv = 1.f / sum;
            *(float4*)&s_route[base] = make_float4(e0 * inv, e1 * inv, e2 * inv, e3 * inv);
            wave_lds_fence();   // wave-private: no s_barrier

            #pragma unroll
            for (int p = 0; p < 4; ++p) pre[p] = f4zero();
            const int rb = w * WSTR + (l >> 2);   // + p*PSTR + ii*16 ; o = l>>2
            #pragma unroll
            for (int p = 0; p < 4; ++p) {
                #pragma unroll
                for (int ii = 0; ii < 4; ++ii) {
                    const float r = s_route[rb + p * PSTR + ii * 16];  // broadcast read
                    fma4(pre[p], r, v[ii][p]);
                }
            }
        }

        // stage partial preacts (this wave's 4-i contribution, all 4 pixels)
        #pragma unroll
        for (int p = 0; p < 4; ++p)
            *(float4*)&s_part[((w << 2) + p) * 256 + (l << 2)] = pre[p];
        __syncthreads();  // S1

        // combine across 8 waves for pixel p=w (waves 0-3 only), bias, squash
        if (w < 4) {
            float4 acc = bias4;
            #pragma unroll
            for (int wp = 0; wp < 8; ++wp) {
                const float4 q = *(const float4*)&s_part[((wp << 2) + w) * 256 + (l << 2)];
                acc.x += q.x; acc.y += q.y; acc.z += q.z; acc.w += q.w;
            }
            float sq = acc.x * acc.x + acc.y * acc.y + acc.z * acc.z + acc.w * acc.w;
            sq += __shfl_xor(sq, 1);
            sq += __shfl_xor(sq, 2);          // full sum over 16 h (4-lane o-group)
            const float f = sqrtf(sq) / (1.f + sq);   // s/||s|| * ||s||^2/(1+||s||^2)
            *(float4*)&s_act[w * 256 + (l << 2)] =
                make_float4(acc.x * f, acc.y * f, acc.z * f, acc.w * f);
        }
        __syncthreads();  // S2 (also the pre-output sync on it==2)

        if (it < 2) {
            // distances[p][i][o] = sum_h votes * act ; accumulate into logits
            float dacc[4] = {0.f, 0.f, 0.f, 0.f};
            #pragma unroll
            for (int p = 0; p < 4; ++p) {
                const float4 a = *(const float4*)&s_act[p * 256 + (l << 2)];
                #pragma unroll
                for (int ii = 0; ii < 4; ++ii) {
                    float d = v[ii][p].x * a.x + v[ii][p].y * a.y
                            + v[ii][p].z * a.z + v[ii][p].w * a.w;
                    d += __shfl_xor(d, 1);
                    d += __shfl_xor(d, 2);            // full dot over 16 h
                    dacc[ii] = ((l & 3) == p) ? d : dacc[ii]; // lane keeps pixel l&3
                }
            }
            const int lb2 = w * WSTR + (l & 3) * PSTR + (l >> 2); // [w][p=l&3][ii*16+o=l>>2]
            if (it == 0) {
                #pragma unroll
                for (int ii = 0; ii < 4; ++ii) s_logits[lb2 + ii * 16] = dacc[ii];
            } else {
                #pragma unroll
                for (int ii = 0; ii < 4; ++ii) s_logits[lb2 + ii * 16] += dacc[ii];
            }
            wave_lds_fence();   // wave-private: consumed by this wave's softmax next iter
        }
    }

    // ---------------- output: out[b, m, hw0..hw0+3], transposed via s_act
    if (t < 256) {
        float4 o4;
        o4.x = s_act[t];
        o4.y = s_act[256 + t];
        o4.z = s_act[512 + t];
        o4.w = s_act[768 + t];
        *(float4*)(out + (size_t)b * 65536 + (size_t)t * 256 + hw0) = o4;
    }
}

extern "C" void kernel_launch(void* const* d_in, const int* in_sizes, int n_in,
                              void* d_out, int out_size, void* d_ws, size_t ws_size,
                              hipStream_t stream) {
    const float* x    = (const float*)d_in[0];   // (8,32,8,16,16)
    const float* wgt  = (const float*)d_in[1];   // (32,8,256)
    const float* bias = (const float*)d_in[2];   // (16,16,1,1)
    float* out = (float*)d_out;                  // (8,16,16,16,16)
    caps_kernel<<<dim3(512), dim3(512), 0, stream>>>(x, wgt, bias, out);
}